// Round 1
// baseline (749.149 us; speedup 1.0000x reference)
//
#include <hip/hip_runtime.h>
#include <stdint.h>

// N_NODES=500000, N_EDGES=16000000, V_DIM=2, E_DIM=3. MLP: 5->50->20->1.
//
// Lessons:
//  R1/R3: per-edge global fp32 atomics = 32B memory-side txn @ ~20.5G/s. Dead.
//  R5: LDS counting sort gives coalesced record writes; eattr gather is fatal
//      unless staged in LDS.
//  R6: 245-wg agg = latency-bound at 11.5% occupancy -> SPLIT partials.
//  R7/R8: vectorizing agg's loads did NOTHING (256->257us). All pipes idle
//      (VALUBusy 0.7%) => bottleneck is the LDS atomic RMW stream itself:
//      48M lane-atomics / (4 wg/CU co-resident) ~= 3.1 cyc/lane-atomic.
//  R9 (this round): de-atomize hist+bin via wave ballot ranking. Per 64-edge
//      batch: eq-mask from 8 ballots, rank = popc(eq & below), leader-only
//      plain LDS bump of a per-(bin,wave)-private counter (wave lockstep +
//      column privacy => race-free without atomics). agg left UNCHANGED as
//      the control; it is next round's target (pass-2 full sort + fused
//      gather-MLP).

#define SB_SHIFT 11      // 2048 nodes per super-bucket
#define SB_NODES 2048
#define NSB 256          // max super-buckets -> n_nodes <= 524288
#define CHUNK 4096       // edges per wg in hist/bin
#define TB 512           // bin/agg threads (8 waves)
#define THREADS 256
#define SPLIT 4          // record-range splits per super-bucket in agg
#define HWS 9            // bin per-(bin,wave) counter stride: 8 waves + pad
#define HWS_H 5          // hist stride: 4 waves + pad

typedef float vf4 __attribute__((ext_vector_type(4)));
typedef int vi4 __attribute__((ext_vector_type(4)));
typedef unsigned int vu2 __attribute__((ext_vector_type(2)));

// equal-key mask among lanes in vm for an 8-bit key b (per-lane result)
__device__ __forceinline__ uint64_t eq_mask8(int b, uint64_t vm) {
  uint64_t eq = vm;
#pragma unroll
  for (int bit = 0; bit < 8; ++bit) {
    uint64_t bl = __ballot((b >> bit) & 1);
    eq &= ((b >> bit) & 1) ? bl : ~bl;
  }
  return eq;
}

// ------------- K0: per-wg histogram -> counts_T[b*nwpad + w] (transposed) ----
// Zero atomics: ballot-group counting into per-(bin,wave)-private counters.
__global__ __launch_bounds__(THREADS) void hist_kernel(
    const int* __restrict__ tgt, int n_edges, int* __restrict__ counts_T,
    int nwpad) {
  __shared__ unsigned int hw[NSB * HWS_H];
  for (int i = threadIdx.x; i < NSB * HWS_H; i += THREADS) hw[i] = 0;
  __syncthreads();
  const int tid = threadIdx.x;
  const int lane = tid & 63;
  const int w = tid >> 6;  // 0..3
  const uint64_t below = (1ull << lane) - 1;
  const int wg = blockIdx.x;
  const int base = wg * CHUNK;
  const int end = min(base + CHUNK, n_edges);
  const int m = end - base;
  const int nq = m >> 2;
  const vi4* tp = (const vi4*)(tgt + base);
#pragma unroll
  for (int k = 0; k < CHUNK / 4 / THREADS; ++k) {  // 4 quad-batches
    int j = k * THREADS + tid;
    bool qv = j < nq;
    vi4 t4;
    t4.x = 0; t4.y = 0; t4.z = 0; t4.w = 0;
    if (qv) t4 = tp[j];
    uint64_t vm = __ballot(qv);
#pragma unroll
    for (int c = 0; c < 4; ++c) {
      int b = t4[c] >> SB_SHIFT;
      uint64_t eq = eq_mask8(b, vm);
      if (qv && (eq & below) == 0)  // leader of its equal-key group
        hw[b * HWS_H + w] += (unsigned int)__popcll(eq);
    }
  }
  {  // remainder edges (m % 4)
    int i = (nq << 2) + tid;
    bool v2 = i < m;
    uint64_t vm = __ballot(v2);
    if (vm) {
      int t = 0;
      if (v2) t = tgt[base + i];
      int b = t >> SB_SHIFT;
      uint64_t eq = eq_mask8(b, vm);
      if (v2 && (eq & below) == 0)
        hw[b * HWS_H + w] += (unsigned int)__popcll(eq);
    }
  }
  __syncthreads();
  // scattered 4B stores, but concurrent wgs (adjacent wg) write adjacent
  // addresses in each row -> L2 merges into full lines.
  for (int i = tid; i < NSB; i += THREADS) {
    unsigned int s = 0;
#pragma unroll
    for (int w2 = 0; w2 < THREADS / 64; ++w2) s += hw[i * HWS_H + w2];
    counts_T[(size_t)i * nwpad + wg] = (int)s;
  }
}

// ---- S1: block b scans its contiguous row counts_T[b][0..nw) (in place) ----
__global__ __launch_bounds__(THREADS) void scan1_kernel(
    int* __restrict__ counts_T, int nw, int nwpad, int* __restrict__ row_total) {
  __shared__ int part[THREADS];
  int b = blockIdx.x;
  int* row = counts_T + (size_t)b * nwpad;
  int per = (nw + THREADS - 1) / THREADS;
  int w0 = threadIdx.x * per;
  int w1 = min(w0 + per, nw);
  int s = 0;
  for (int w = w0; w < w1; ++w) s += row[w];
  part[threadIdx.x] = s;
  __syncthreads();
  for (int off = 1; off < THREADS; off <<= 1) {
    int v = (threadIdx.x >= off) ? part[threadIdx.x - off] : 0;
    __syncthreads();
    part[threadIdx.x] += v;
    __syncthreads();
  }
  int run = part[threadIdx.x] - s;
  for (int w = w0; w < w1; ++w) {
    int v = row[w];
    row[w] = run;
    run += v;
  }
  if (threadIdx.x == THREADS - 1) row_total[b] = part[THREADS - 1];
}

// ---- S2: sb_base = exclusive scan of row_total padded up to x4 -------------
__global__ __launch_bounds__(THREADS) void scan2_kernel(
    const int* __restrict__ row_total, int* __restrict__ sb_base) {
  __shared__ int part[THREADS];
  int v = (row_total[threadIdx.x] + 3) & ~3;  // padded span
  part[threadIdx.x] = v;
  __syncthreads();
  for (int off = 1; off < THREADS; off <<= 1) {
    int u = (threadIdx.x >= off) ? part[threadIdx.x - off] : 0;
    __syncthreads();
    part[threadIdx.x] += u;
    __syncthreads();
  }
  sb_base[threadIdx.x] = part[threadIdx.x] - v;  // x4-aligned base
}

// ------- K1: atomic-free LDS counting sort + LDS-staged eattr ---------------
__global__ __launch_bounds__(TB) void bin_kernel(
    const int* __restrict__ tgt, const float* __restrict__ eattr, int n_edges,
    const int* __restrict__ rowpref_T, int nwpad,
    const int* __restrict__ sb_base,
    float* __restrict__ rec3, unsigned short* __restrict__ ids) {
  __shared__ float eattr_s[CHUNK * 3];     // 48 KB
  __shared__ unsigned short inv[CHUNK];    // 8 KB
  __shared__ unsigned int hw[NSB * HWS];   // per-(bin,wave) counts -> bases, 9 KB
  __shared__ int excl[NSB];
  __shared__ int wb[NSB];
  __shared__ int part[NSB];

  const int tid = threadIdx.x;
  const int lane = tid & 63;
  const int w = tid >> 6;  // 0..7
  const uint64_t below = (1ull << lane) - 1;
  const int wg = blockIdx.x;
  const int base = wg * CHUNK;
  const int end = min(base + CHUNK, n_edges);
  const int m = end - base;
  const int nq = m >> 2;

  for (int i = tid; i < NSB * HWS; i += TB) hw[i] = 0;
  __syncthreads();

  // P1: ballot-ranked counting. Per edge, store (bin<<16 | rank-in-(bin,wave))
  // in registers; leaders bump the wave-private plain LDS counter. Wave
  // lockstep orders the read (all lanes) before the leader write, and only
  // wave w touches column w -> no atomics needed.
  unsigned int pk[2 * 4 + 1];
  const vi4* tp = (const vi4*)(tgt + base);
#pragma unroll
  for (int k = 0; k < CHUNK / 4 / TB; ++k) {  // 2 quad-batches
    int j = k * TB + tid;
    bool qv = j < nq;
    vi4 t4;
    t4.x = 0; t4.y = 0; t4.z = 0; t4.w = 0;
    if (qv) t4 = tp[j];
    uint64_t vm = __ballot(qv);
#pragma unroll
    for (int c = 0; c < 4; ++c) {
      int b = t4[c] >> SB_SHIFT;
      uint64_t eq = eq_mask8(b, vm);
      unsigned int r = (unsigned int)__popcll(eq & below);
      unsigned int old = 0;
      if (qv) old = hw[b * HWS + w];
      pk[k * 4 + c] = ((unsigned int)b << 16) | (old + r);
      if (qv && r == 0)  // group leader
        hw[b * HWS + w] = old + (unsigned int)__popcll(eq);
    }
  }
  {  // remainder edges (m % 4)
    int i = (nq << 2) + tid;
    bool v2 = i < m;
    uint64_t vm = __ballot(v2);
    pk[8] = 0xFFFFFFFFu;
    if (vm) {
      int t = 0;
      if (v2) t = tgt[base + i];
      int b = t >> SB_SHIFT;
      uint64_t eq = eq_mask8(b, vm);
      unsigned int r = (unsigned int)__popcll(eq & below);
      if (v2) {
        unsigned int old = hw[b * HWS + w];
        pk[8] = ((unsigned int)b << 16) | (old + r);
        if (r == 0) hw[b * HWS + w] = old + (unsigned int)__popcll(eq);
      }
    }
  }

  // P0: stage this chunk's eattr into LDS
  {
    const float* src = eattr + (size_t)base * 3;
    int nd = m * 3;
    int nv = nd >> 2;
    const vf4* s4 = (const vf4*)src;
    for (int i = tid; i < nv; i += TB) {
      vf4 v = __builtin_nontemporal_load(s4 + i);
      *(vf4*)(&eattr_s[i * 4]) = v;
    }
    for (int i = (nv << 2) + tid; i < nd; i += TB) eattr_s[i] = src[i];
  }
  __syncthreads();

  // P2: hw -> per-(bin,wave) exclusive bases; part = per-bin totals; scan.
  int myct = 0;
  if (tid < NSB) {
    unsigned int s = 0;
#pragma unroll
    for (int w2 = 0; w2 < TB / 64; ++w2) {
      unsigned int v = hw[tid * HWS + w2];
      hw[tid * HWS + w2] = s;
      s += v;
    }
    myct = (int)s;
    part[tid] = myct;
  }
  __syncthreads();
  for (int off = 1; off < NSB; off <<= 1) {
    int v = 0;
    if (tid < NSB && tid >= off) v = part[tid - off];
    __syncthreads();
    if (tid < NSB) part[tid] += v;
    __syncthreads();
  }
  if (tid < NSB) {
    excl[tid] = part[tid] - myct;
    wb[tid] = sb_base[tid] + rowpref_T[(size_t)tid * nwpad + wg];
  }
  __syncthreads();

  // P3: scatter ranks -> inv (plain stores; positions are unique by constr.)
#pragma unroll
  for (int k = 0; k < CHUNK / 4 / TB; ++k) {
    int j = k * TB + tid;
    if (j < nq) {
#pragma unroll
      for (int c = 0; c < 4; ++c) {
        unsigned int p = pk[k * 4 + c];
        int b = (int)(p >> 16);
        int pos = excl[b] + (int)hw[b * HWS + w] + (int)(p & 0xFFFFu);
        inv[pos] = (unsigned short)((j << 2) + c);
      }
    }
  }
  {
    int i = (nq << 2) + tid;
    if (i < m) {
      unsigned int p = pk[8];
      int b = (int)(p >> 16);
      int pos = excl[b] + (int)hw[b * HWS + w] + (int)(p & 0xFFFFu);
      inv[pos] = (unsigned short)i;
    }
  }
  __syncthreads();

  // P4: emit in sorted order -> coalesced runs; eattr from LDS, tgt from L1.
  for (int sidx = tid; sidx < m; sidx += TB) {
    int el = inv[sidx];
    int t = tgt[base + el];
    int bk = t >> SB_SHIFT;
    int slot = wb[bk] + (sidx - excl[bk]);
    float a0 = eattr_s[el * 3 + 0];
    float a1 = eattr_s[el * 3 + 1];
    float a2 = eattr_s[el * 3 + 2];
    size_t o = (size_t)slot * 3;
    rec3[o + 0] = a0;
    rec3[o + 1] = a1;
    rec3[o + 2] = a2;
    ids[slot] = (unsigned short)(t & (SB_NODES - 1));
  }
}

// ---- K2: per-(SB, split) LDS aggregation (UNCHANGED this round: control) ---
__global__ __launch_bounds__(TB) void agg_kernel(
    const float* __restrict__ rec3, const unsigned short* __restrict__ ids,
    const int* __restrict__ sb_base, const int* __restrict__ row_total,
    float* __restrict__ partials, size_t pstride) {
  __shared__ float acc[SB_NODES * 3];  // 24 KB
  int tid = threadIdx.x;
  for (int i = tid; i < SB_NODES * 3; i += TB) acc[i] = 0.f;
  __syncthreads();
  int b = blockIdx.x / SPLIT;
  int j = blockIdx.x % SPLIT;
  int cnt = row_total[b];
  int rbase = sb_base[b];  // x4-aligned
  int q = (((cnt + SPLIT - 1) / SPLIT) + 3) & ~3;  // x4 split size
  int lo = j * q;
  int hi = min(cnt, lo + q);
  int len = hi - lo;
  if (len > 0) {
    int nq = len >> 2;  // full quads
    for (int k = tid; k < nq; k += TB) {
      int s0 = rbase + lo + (k << 2);
      const vf4* rp = (const vf4*)(rec3 + (size_t)s0 * 3);
      vf4 r0 = rp[0];
      vf4 r1 = rp[1];
      vf4 r2 = rp[2];
      vu2 u = *(const vu2*)(ids + s0);
      int l0 = u.x & 0xFFFF;
      int l1 = u.x >> 16;
      int l2 = u.y & 0xFFFF;
      int l3 = u.y >> 16;
      atomicAdd(&acc[l0 * 3 + 0], r0.x);
      atomicAdd(&acc[l0 * 3 + 1], r0.y);
      atomicAdd(&acc[l0 * 3 + 2], r0.z);
      atomicAdd(&acc[l1 * 3 + 0], r0.w);
      atomicAdd(&acc[l1 * 3 + 1], r1.x);
      atomicAdd(&acc[l1 * 3 + 2], r1.y);
      atomicAdd(&acc[l2 * 3 + 0], r1.z);
      atomicAdd(&acc[l2 * 3 + 1], r1.w);
      atomicAdd(&acc[l2 * 3 + 2], r2.x);
      atomicAdd(&acc[l3 * 3 + 0], r2.y);
      atomicAdd(&acc[l3 * 3 + 1], r2.z);
      atomicAdd(&acc[l3 * 3 + 2], r2.w);
    }
    for (int i = lo + (nq << 2) + tid; i < hi; i += TB) {
      size_t s = (size_t)(rbase + i);
      float r0 = rec3[s * 3 + 0];
      float r1 = rec3[s * 3 + 1];
      float r2 = rec3[s * 3 + 2];
      int local = ids[s];
      atomicAdd(&acc[local * 3 + 0], r0);
      atomicAdd(&acc[local * 3 + 1], r1);
      atomicAdd(&acc[local * 3 + 2], r2);
    }
  }
  __syncthreads();
  float* pj = partials + (size_t)j * pstride + (((size_t)b << SB_SHIFT) * 3);
  for (int i = tid; i < SB_NODES * 3; i += TB) pj[i] = acc[i];
}

// ---------------- K3: reduce SPLIT partials + MLP ---------------------------
__global__ __launch_bounds__(THREADS) void mlp_reduce_kernel(
    const float* __restrict__ va, const float* __restrict__ partials,
    size_t pstride, const float* __restrict__ W1, const float* __restrict__ b1,
    const float* __restrict__ W2, const float* __restrict__ b2,
    const float* __restrict__ W3, const float* __restrict__ b3,
    float* __restrict__ out, int n) {
  int i = blockIdx.x * THREADS + threadIdx.x;
  if (i >= n) return;
  float a0 = 0.f, a1 = 0.f, a2 = 0.f;
#pragma unroll
  for (int j = 0; j < SPLIT; ++j) {
    const float* p = partials + (size_t)j * pstride + (size_t)i * 3;
    a0 += p[0];
    a1 += p[1];
    a2 += p[2];
  }
  float x[5];
  float2 v = ((const float2*)va)[i];
  x[0] = v.x;
  x[1] = v.y;
  x[2] = a0;
  x[3] = a1;
  x[4] = a2;

  float h1[50];
#pragma unroll
  for (int j = 0; j < 50; ++j) {
    float s = b1[j];
#pragma unroll
    for (int k = 0; k < 5; ++k) s = fmaf(W1[j * 5 + k], x[k], s);
    h1[j] = fmaxf(s, 0.0f);
  }
  float h2[20];
#pragma unroll
  for (int j = 0; j < 20; ++j) {
    float s = b2[j];
#pragma unroll
    for (int k = 0; k < 50; ++k) s = fmaf(W2[j * 50 + k], h1[k], s);
    h2[j] = fmaxf(s, 0.0f);
  }
  float s = b3[0];
#pragma unroll
  for (int k = 0; k < 20; ++k) s = fmaf(W3[k], h2[k], s);
  out[i] = s;
}

// ---------------- fallback (tiny ws): direct device atomics -----------------
__global__ __launch_bounds__(THREADS) void scatter_dev_kernel(
    const int* __restrict__ tgt, const float* __restrict__ eattr,
    float* __restrict__ agg, int n_edges) {
  int e = blockIdx.x * blockDim.x + threadIdx.x;
  if (e >= n_edges) return;
  int d = tgt[e];
  atomicAdd(&agg[d * 4 + 0], eattr[(size_t)e * 3 + 0]);
  atomicAdd(&agg[d * 4 + 1], eattr[(size_t)e * 3 + 1]);
  atomicAdd(&agg[d * 4 + 2], eattr[(size_t)e * 3 + 2]);
}

__global__ __launch_bounds__(THREADS) void mlp_table_kernel(
    const float* __restrict__ va, const vf4* __restrict__ table,
    const float* __restrict__ W1, const float* __restrict__ b1,
    const float* __restrict__ W2, const float* __restrict__ b2,
    const float* __restrict__ W3, const float* __restrict__ b3,
    float* __restrict__ out, int n) {
  int i = blockIdx.x * blockDim.x + threadIdx.x;
  if (i >= n) return;
  float x[5];
  float2 v = ((const float2*)va)[i];
  vf4 t = table[i];
  x[0] = v.x; x[1] = v.y; x[2] = t.x; x[3] = t.y; x[4] = t.z;
  float h1[50];
#pragma unroll
  for (int j = 0; j < 50; ++j) {
    float s = b1[j];
#pragma unroll
    for (int k = 0; k < 5; ++k) s = fmaf(W1[j * 5 + k], x[k], s);
    h1[j] = fmaxf(s, 0.0f);
  }
  float h2[20];
#pragma unroll
  for (int j = 0; j < 20; ++j) {
    float s = b2[j];
#pragma unroll
    for (int k = 0; k < 50; ++k) s = fmaf(W2[j * 50 + k], h1[k], s);
    h2[j] = fmaxf(s, 0.0f);
  }
  float s = b3[0];
#pragma unroll
  for (int k = 0; k < 20; ++k) s = fmaf(W3[k], h2[k], s);
  out[i] = s;
}

extern "C" void kernel_launch(void* const* d_in, const int* in_sizes, int n_in,
                              void* d_out, int out_size, void* d_ws, size_t ws_size,
                              hipStream_t stream) {
  const float* vertex_attr = (const float*)d_in[0];
  const int* edge_index = (const int*)d_in[1];  // [2, E] int32
  const float* edge_attr = (const float*)d_in[2];
  const float* W1 = (const float*)d_in[3];
  const float* b1 = (const float*)d_in[4];
  const float* W2 = (const float*)d_in[5];
  const float* b2 = (const float*)d_in[6];
  const float* W3 = (const float*)d_in[7];
  const float* b3 = (const float*)d_in[8];
  float* out = (float*)d_out;

  const int n_nodes = in_sizes[0] / 2;   // V_DIM = 2
  const int n_edges = in_sizes[2] / 3;   // E_DIM = 3
  const int* tgt = edge_index + n_edges; // row 1 = targets

  const int nsb_rt = (n_nodes + SB_NODES - 1) >> SB_SHIFT;
  const int nw = (n_edges + CHUNK - 1) / CHUNK;
  const int nwpad = nw;
  const size_t Np = (size_t)nsb_rt << SB_SHIFT;  // padded node count
  const size_t pstride = Np * 3;                 // floats per partial table
  const int rec_cap = n_edges + 4 * NSB;         // slack for x4 base padding

  // ws layout (aligned): [rec3 cap*12][ids cap*2][row_total][sb_base]
  //                      [counts_T NSB*nwpad][partials SPLIT*Np*12]
  char* ws = (char*)d_ws;
  size_t o = 0;
  float* rec3 = (float*)(ws + o);
  o += (size_t)rec_cap * 3 * sizeof(float);
  o = (o + 255) & ~(size_t)255;
  unsigned short* ids = (unsigned short*)(ws + o);
  o += (size_t)rec_cap * sizeof(unsigned short);
  o = (o + 255) & ~(size_t)255;
  int* row_total = (int*)(ws + o);
  o += NSB * sizeof(int);
  int* sb_base = (int*)(ws + o);
  o += NSB * sizeof(int);
  o = (o + 255) & ~(size_t)255;
  int* counts_T = (int*)(ws + o);
  o += (size_t)NSB * nwpad * sizeof(int);
  o = (o + 255) & ~(size_t)255;
  float* partials = (float*)(ws + o);
  o += (size_t)SPLIT * pstride * sizeof(float);
  const size_t need = o;

  if (nsb_rt <= NSB && ws_size >= need) {
    hist_kernel<<<nw, THREADS, 0, stream>>>(tgt, n_edges, counts_T, nwpad);
    scan1_kernel<<<NSB, THREADS, 0, stream>>>(counts_T, nw, nwpad, row_total);
    scan2_kernel<<<1, THREADS, 0, stream>>>(row_total, sb_base);
    bin_kernel<<<nw, TB, 0, stream>>>(tgt, edge_attr, n_edges, counts_T, nwpad,
                                      sb_base, rec3, ids);
    agg_kernel<<<nsb_rt * SPLIT, TB, 0, stream>>>(rec3, ids, sb_base,
                                                  row_total, partials, pstride);
    mlp_reduce_kernel<<<(n_nodes + THREADS - 1) / THREADS, THREADS, 0,
                        stream>>>(vertex_attr, partials, pstride, W1, b1, W2,
                                  b2, W3, b3, out, n_nodes);
  } else {
    vf4* table = (vf4*)ws;
    hipMemsetAsync(table, 0, (size_t)n_nodes * sizeof(vf4), stream);
    const int nblk = (n_edges + THREADS - 1) / THREADS;
    scatter_dev_kernel<<<nblk, THREADS, 0, stream>>>(tgt, edge_attr,
                                                     (float*)table, n_edges);
    mlp_table_kernel<<<(n_nodes + THREADS - 1) / THREADS, THREADS, 0, stream>>>(
        vertex_attr, table, W1, b1, W2, b2, W3, b3, out, n_nodes);
  }
}